// Round 12
// baseline (455.889 us; speedup 1.0000x reference)
//
#include <hip/hip_runtime.h>

// softmax(Q.V^T).V — deferred-normalization pipeline (fp16):
//   conv:  Q -> Qh fp16;  V -> Vh fp16 + VT (=Vh^T)
//   GEMM1 (MODE 1): S-tile = Qh.Vh^T; per-wave epilogue per 64-col chunk:
//       m_c = chunk row-max (16-lane shfl), P = fp16(exp(S-m_c)), s_c = row-sum.
//   k_stats: r2'[c] = exp(m_c - m_g)/denom (fp16, normalization folded).
//   GEMM2 (MODE 2): out = sum_c (P_c * r2'[c]) . VT_c^T  (exact softmax.V)
// GEMM geometry (this round — high-occupancy): 128x128 tile, 4 waves (2x2,
// 64x64/wave), BK=32, SINGLE-buffered 16KB LDS, 2-sync loop. Rationale:
// per-step rate tracks blocks/CU (R5: 4/CU -> 1.72us/step vs R9 1/CU 2.73);
// 256² 8-phase can't exceed 1 block/CU (acc=128 VGPR). 128² + 64 VGPR acc +
// 16KB LDS gives 3-4 resident blocks/CU — inter-block overlap hides the
// vmcnt(0)+barrier drain (m114). Perfect swizzle for 64B rows:
// granule ^= (row ^ row>>2)&3 (worst 2-way = free), via pre-swizzled src.

#define B_ 16
#define LQ_ 2048
#define LV_ 2048
#define DD_ 1024

typedef unsigned short u16;
typedef _Float16 f16x8 __attribute__((ext_vector_type(8)));
typedef __attribute__((ext_vector_type(4))) float f32x4;
typedef __attribute__((ext_vector_type(4))) unsigned short u16x4;

__device__ __forceinline__ u16 f2h(float x) {
  union { _Float16 h; u16 u; } c;
  c.h = (_Float16)x;
  return c.u;
}

__device__ __forceinline__ void gload16(const u16* g, u16* lds) {
  __builtin_amdgcn_global_load_lds(
      (const __attribute__((address_space(1))) void*)g,
      (__attribute__((address_space(3))) void*)lds, 16, 0, 0);
}

// ---------------- 128x128 BK=32 high-occupancy GEMM ----------------
// MODE 1: A.B^T -> P=exp(S-m_chunk) fp16 + per-64-col-chunk m/s tables
// MODE 2: sum_c (A_c*r2'[c]).B_c^T -> fp32 (deferred normalization)
template <int K, int MODE>
__global__ __launch_bounds__(256, 4) void k_gemm(
    const u16* __restrict__ A, const u16* __restrict__ B,
    u16* __restrict__ Pout, float* __restrict__ Fout,
    const u16* __restrict__ r2tab,
    float* __restrict__ mtab, float* __restrict__ stab,
    int N, int lda, int ldb, size_t aBatch, size_t bBatch, size_t cBatch) {
  __shared__ u16 ldsA[128 * 32];                       // 8 KB
  __shared__ u16 ldsB[128 * 32];                       // 8 KB
  __shared__ u16 ldsR2[(MODE == 2) ? (K / 64) * 128 : 64];

  // XCD-aware bijective remap (nwg % 8 == 0)
  int bx, by, bz;
  {
    const int gx = gridDim.x, gy = gridDim.y;
    const int lid = blockIdx.x + gx * (blockIdx.y + gy * blockIdx.z);
    const int nwg = gx * gy * gridDim.z;
    const int q = nwg >> 3;
    const int nid = (lid & 7) * q + (lid >> 3);
    bx = nid % gx;
    const int rem = nid / gx;
    by = rem % gy;
    bz = rem / gy;
  }

  const int tid = threadIdx.x;
  const int w = tid >> 6, l = tid & 63;
  const int m0 = by << 7, n0 = bx << 7;
  const int wr64 = (w >> 1) * 64, wc64 = (w & 1) * 64;
  const int fr = l & 15, kx = l >> 4;                  // frag row / k-granule
  const int rg4 = kx * 4, cc = fr;
  // read-side swizzled granule offset (elems): (kx ^ f(fr)) * 8
  const int gsw = ((kx ^ ((fr ^ (fr >> 2)) & 3)) << 3);
  // stage-side: thread t covers LDS rows rd, rd+64 with granule gd = t&3
  const int rd = tid >> 2, gd = tid & 3;
  const int gsA0 = ((gd ^ ((rd ^ (rd >> 2)) & 3)) << 3);
  const int rd1 = rd + 64;
  const int gsA1 = ((gd ^ ((rd1 ^ (rd1 >> 2)) & 3)) << 3);

  const u16* Ab = A + (size_t)bz * aBatch;
  const u16* Bb = B + (size_t)bz * bBatch;

  if constexpr (MODE == 2) {
    for (int i = tid; i < (K / 64) * 128; i += 256)
      ldsR2[i] = r2tab[((size_t)bz * 32 + (i >> 7)) * 2048 + m0 + (i & 127)];
    __syncthreads();
  }

  f32x4 acc[4][4];
#pragma unroll
  for (int i = 0; i < 4; ++i)
#pragma unroll
    for (int j = 0; j < 4; ++j) acc[i][j] = (f32x4){0.f, 0.f, 0.f, 0.f};
  f16x8 af[4], bf[4];
  _Float16 r2h[4];

  for (int kt = 0; kt < K; kt += 32) {
    // stage A,B 128x32 tiles (linear LDS dest, inverse-swizzled global src)
    {
      const u16* ga = Ab + (size_t)(m0 + rd) * lda + kt;
      const u16* gb = Bb + (size_t)(n0 + rd) * ldb + kt;
      gload16(ga + gsA0, &ldsA[rd * 32 + gd * 8]);
      gload16(ga + (size_t)64 * lda + gsA1, &ldsA[rd1 * 32 + gd * 8]);
      gload16(gb + gsA0, &ldsB[rd * 32 + gd * 8]);
      gload16(gb + (size_t)64 * ldb + gsA1, &ldsB[rd1 * 32 + gd * 8]);
    }
    __syncthreads();
    if constexpr (MODE == 2) {
      if ((kt & 63) == 0) {
        const int chb = (kt >> 6) * 128;
#pragma unroll
        for (int m_ = 0; m_ < 4; ++m_)
          r2h[m_] = *(const _Float16*)&ldsR2[chb + wr64 + m_ * 16 + fr];
      }
    }
#pragma unroll
    for (int m_ = 0; m_ < 4; ++m_) {
      af[m_] = *(const f16x8*)&ldsA[(wr64 + m_ * 16 + fr) * 32 + gsw];
      if constexpr (MODE == 2) af[m_] = af[m_] * r2h[m_];
    }
#pragma unroll
    for (int n_ = 0; n_ < 4; ++n_)
      bf[n_] = *(const f16x8*)&ldsB[(wc64 + n_ * 16 + fr) * 32 + gsw];
#pragma unroll
    for (int m_ = 0; m_ < 4; ++m_)
#pragma unroll
      for (int n_ = 0; n_ < 4; ++n_)
        acc[m_][n_] = __builtin_amdgcn_mfma_f32_16x16x32_f16(
            af[m_], bf[n_], acc[m_][n_], 0, 0, 0);
    __syncthreads();
  }

  // C/D layout: col = lane&15, row = (lane>>4)*4 + j   [m89-verified]
  if constexpr (MODE == 1) {
    // per-wave fused softmax epilogue: each wave owns one 64-col chunk
    u16* Pc = Pout + (size_t)bz * ((size_t)2048 * 2048);
    const int chunk = bx * 2 + (w & 1);  // 0..31
    const size_t tbase = ((size_t)bz * 32 + chunk) * 2048 + m0;
#pragma unroll
    for (int mf = 0; mf < 4; ++mf) {
      float mt4[4], st4[4];
#pragma unroll
      for (int j = 0; j < 4; ++j) {
        const int r_ = wr64 + mf * 16 + rg4 + j;
        float v = fmaxf(fmaxf(acc[mf][0][j], acc[mf][1][j]),
                        fmaxf(acc[mf][2][j], acc[mf][3][j]));
#pragma unroll
        for (int off = 1; off < 16; off <<= 1) v = fmaxf(v, __shfl_xor(v, off, 64));
        const float e0 = __expf(acc[mf][0][j] - v);
        const float e1 = __expf(acc[mf][1][j] - v);
        const float e2 = __expf(acc[mf][2][j] - v);
        const float e3 = __expf(acc[mf][3][j] - v);
        u16* pr = Pc + (size_t)(m0 + r_) * 2048 + n0 + wc64 + cc;
        pr[0] = f2h(e0);
        pr[16] = f2h(e1);
        pr[32] = f2h(e2);
        pr[48] = f2h(e3);
        float s = (e0 + e1) + (e2 + e3);
#pragma unroll
        for (int off = 1; off < 16; off <<= 1) s += __shfl_xor(s, off, 64);
        mt4[j] = v;
        st4[j] = s;
      }
      if ((l & 15) == 0) {
        const int r0 = wr64 + mf * 16 + rg4;
        *(float4*)&mtab[tbase + r0] = make_float4(mt4[0], mt4[1], mt4[2], mt4[3]);
        *(float4*)&stab[tbase + r0] = make_float4(st4[0], st4[1], st4[2], st4[3]);
      }
    }
  } else {
    float* Cb = Fout + (size_t)bz * cBatch;
#pragma unroll
    for (int mf = 0; mf < 4; ++mf)
#pragma unroll
      for (int nf = 0; nf < 4; ++nf) {
        float* cp = Cb + (size_t)(m0 + wr64 + mf * 16 + rg4) * N + n0 + wc64 + nf * 16 + cc;
#pragma unroll
        for (int j = 0; j < 4; ++j) cp[(size_t)j * N] = acc[mf][nf][j];
      }
  }
}

// ---------------- stats kernel: fold normalization into r2' ---------
__global__ __launch_bounds__(256) void k_stats(const float* __restrict__ mtab,
                                               const float* __restrict__ stab,
                                               u16* __restrict__ r2tab) {
  const int r = blockIdx.x * 256 + threadIdx.x;  // 0..2047
  const int bz = blockIdx.y;
  float m[32], s[32], mg = -3.0e38f;
#pragma unroll
  for (int t = 0; t < 32; ++t) {
    m[t] = mtab[((size_t)bz * 32 + t) * 2048 + r];
    s[t] = stab[((size_t)bz * 32 + t) * 2048 + r];
    mg = fmaxf(mg, m[t]);
  }
  float denom = 0.f;
  float f[32];
#pragma unroll
  for (int t = 0; t < 32; ++t) {
    f[t] = __expf(m[t] - mg);
    denom += s[t] * f[t];
  }
  const float inv = 1.0f / denom;
#pragma unroll
  for (int t = 0; t < 32; ++t)
    r2tab[((size_t)bz * 32 + t) * 2048 + r] = f2h(f[t] * inv);
}

// ---------------- aux kernels ----------------
__global__ __launch_bounds__(256) void k_conv_q(const float* __restrict__ in,
                                                u16* __restrict__ hi_o, int nrows) {
  int t = blockIdx.x * 256 + threadIdx.x;
  int total = nrows * (DD_ / 4);
  if (t >= total) return;
  int row = t >> 8;
  int c4 = (t & 255) << 2;
  float4 v = *(const float4*)(in + (size_t)row * DD_ + c4);
  u16x4 hi;
  hi.x = f2h(v.x);
  hi.y = f2h(v.y);
  hi.z = f2h(v.z);
  hi.w = f2h(v.w);
  *(u16x4*)(hi_o + (size_t)row * DD_ + c4) = hi;
}

__global__ __launch_bounds__(256) void k_conv_vt(const float* __restrict__ V,
                                                 u16* __restrict__ Vh,
                                                 u16* __restrict__ VT) {
  __shared__ u16 tile[64][65];
  const int d0 = blockIdx.x * 64, v0 = blockIdx.y * 64;
  const size_t boff = (size_t)blockIdx.z * LV_ * DD_;
  const float* Vb = V + boff;
  u16* Vhb = Vh + boff;
  u16* VTb = VT + (size_t)blockIdx.z * DD_ * LV_;
  const int t = threadIdx.x;
  const int r = t >> 4, c4 = (t & 15) * 4;
#pragma unroll
  for (int i = 0; i < 4; ++i) {
    int row = r + i * 16;
    float4 x = *(const float4*)(Vb + (size_t)(v0 + row) * DD_ + d0 + c4);
    u16x4 h;
    h.x = f2h(x.x);
    h.y = f2h(x.y);
    h.z = f2h(x.z);
    h.w = f2h(x.w);
    *(u16x4*)(Vhb + (size_t)(v0 + row) * DD_ + d0 + c4) = h;
    tile[row][c4 + 0] = h.x;
    tile[row][c4 + 1] = h.y;
    tile[row][c4 + 2] = h.z;
    tile[row][c4 + 3] = h.w;
  }
  __syncthreads();
#pragma unroll
  for (int i = 0; i < 4; ++i) {
    int row = r + i * 16;
    u16x4 o;
    o.x = tile[c4 + 0][row];
    o.y = tile[c4 + 1][row];
    o.z = tile[c4 + 2][row];
    o.w = tile[c4 + 3][row];
    *(u16x4*)(VTb + (size_t)(d0 + row) * LV_ + v0 + c4) = o;
  }
}

extern "C" void kernel_launch(void* const* d_in, const int* in_sizes, int n_in,
                              void* d_out, int out_size, void* d_ws, size_t ws_size,
                              hipStream_t stream) {
  const float* Q = (const float*)d_in[0];
  const float* V = (const float*)d_in[1];
  float* out = (float*)d_out;

  const size_t qv_e = (size_t)LQ_ * DD_;      // 2M elems
  const size_t vt_e = (size_t)DD_ * LV_;      // 2M
  const size_t p_e = (size_t)LQ_ * LV_;       // 4M
  const size_t tab_e = (size_t)32 * 2048;     // per-batch table entries
  const size_t per_batch =
      qv_e * 2 * 2 + vt_e * 2 + p_e * 2 + tab_e * 4 * 2 + tab_e * 2;

  int nb = (int)(ws_size / per_batch);
  if (nb < 1) nb = 1;
  if (nb > B_) nb = B_;

  char* wp = (char*)d_ws;
  u16* Qh = (u16*)wp;    wp += (size_t)nb * qv_e * 2;
  u16* Vh = (u16*)wp;    wp += (size_t)nb * qv_e * 2;
  u16* VT = (u16*)wp;    wp += (size_t)nb * vt_e * 2;
  u16* P = (u16*)wp;     wp += (size_t)nb * p_e * 2;
  float* mtab = (float*)wp;  wp += (size_t)nb * tab_e * 4;
  float* stab = (float*)wp;  wp += (size_t)nb * tab_e * 4;
  u16* r2tab = (u16*)wp;

  for (int b0 = 0; b0 < B_; b0 += nb) {
    const int cb = (nb < B_ - b0) ? nb : (B_ - b0);
    const int rows = cb * LQ_;
    const int cthreads = rows * (DD_ / 4);
    k_conv_q<<<dim3((cthreads + 255) / 256), dim3(256), 0, stream>>>(
        Q + (size_t)b0 * LQ_ * DD_, Qh, rows);
    k_conv_vt<<<dim3(DD_ / 64, LV_ / 64, cb), dim3(256), 0, stream>>>(
        V + (size_t)b0 * LV_ * DD_, Vh, VT);
    // GEMM1 + per-wave-chunk softmax stats (128² tiles, high occupancy)
    k_gemm<1024, 1><<<dim3(LV_ / 128, LQ_ / 128, cb), dim3(256), 0, stream>>>(
        Qh, Vh, P, nullptr, nullptr, mtab, stab,
        LV_, DD_, DD_, qv_e, qv_e, 0);
    k_stats<<<dim3(LQ_ / 256, cb), dim3(256), 0, stream>>>(mtab, stab, r2tab);
    // GEMM2: out = sum_c (P_c * r2'[c]) . VT_c^T
    k_gemm<2048, 2><<<dim3(DD_ / 128, LQ_ / 128, cb), dim3(256), 0, stream>>>(
        P, VT, nullptr, out + (size_t)b0 * LQ_ * DD_, r2tab, nullptr, nullptr,
        DD_, LV_, LV_, p_e, vt_e, (size_t)LQ_ * DD_);
  }
}